// Round 14
// baseline (170.536 us; speedup 1.0000x reference)
//
#include <hip/hip_runtime.h>
#include <hip/hip_fp16.h>
#include <math.h>

// Problem constants
#define NPIX   131072      // B*H*W = 32*64*64
#define KEMB   512
#define DDIM   64
#define HW     4096        // H*W
#define BSTRIDE 262144     // C*H*W

// d_out flat layout (float32): [loss(1) | out(8388608) | perplexity(1) | indices(131072)]
#define OUT_OFF  1
#define PERP_OFF 8388609
#define IDX_OFF  8388610

typedef __attribute__((ext_vector_type(8))) _Float16 f16x8;    // MFMA A/B frag (4 VGPRs)
typedef __attribute__((ext_vector_type(4))) float f32x4;       // MFMA C/D frag

// SESSION LEDGER (proven on this problem):
//  - R9 = 82us vq_main (total 153.5, best): f16 2-split K-loop, both tables
//    LDS (132KB), 1-tile LDS prefetch pipeline, med3/min top-2, build-after-
//    barrier, 256x1024, 16 waves/CU, fence-LESS ticket finalize.
//  - NEW DIAGNOSIS (R12+R13): hipcc's allocator is LDS-BLIND — it pins 64
//    VGPRs (the 8-waves/SIMD step) even though 132KB LDS caps the block at
//    1/CU, making regs up to 128 free. R12's unroll and R13's x-cache both
//    spilled AT VGPR=64 WITH A 128 CAP (WRITE 91MB scratch signature).
//  - R14 (this): R13's epilogue (x-cache + full-wave output — idea never
//    falsified, only mis-allocated) + amdgpu_waves_per_eu(4,4) to pin the
//    occupancy target at exactly 4 waves/EU -> allocator budget 128 regs.
//  - R11: <=64-reg configs truly spill (live set > 64). Occupancy door CLOSED.
//  - R10: setprio regressed. __threadfence() = ~2x curse (L2 WB/INV). NEVER.
//
// 2-split f16 scheme (absmax 0 in R2..R13): x = h + l/2048 + r, |r|<=2^-21|x|.
// l pre-scaled by 2^11 (exact pow2) stays in f16 normal range. Products kept:
// hh + (h*l'+l'*h)/2048; dropped terms ~1e-4 absolute, and the exact fp32
// top-2 rescore decides the final index.

// ws layout: [0,2048) int counts | [2048,4096) float hnorms | [4096] loss |
//            [4160] done_ctr | [8192,73728) eh_t (f16 high, frag-linear, 64KB) |
//            [73728,139264) el_t (f16 low pre-scaled by 2^11, frag-linear, 64KB)
// frag-linear: idx = ct*1024 + ks*512 + (quad*16+col)*8 + j  (R5-proven).
__global__ void vq_init(const float* __restrict__ emb, int* __restrict__ counts,
                        float* __restrict__ hnorms, float* __restrict__ loss_acc,
                        int* __restrict__ done_ctr,
                        unsigned short* __restrict__ eh_t,
                        unsigned short* __restrict__ el_t) {
    const int k = blockIdx.x;             // code
    const int c = threadIdx.x;            // channel
    const int ct = k >> 4, cl = k & 15;
    const int ks = c >> 5, qd = (c >> 3) & 3, j = c & 7;
    float x = emb[k * DDIM + c];
    _Float16 h = (_Float16)x;             // v_cvt_f16_f32, RTNE
    float r1 = x - (float)h;              // exact (Sterbenz)
    _Float16 l = (_Float16)(r1 * 2048.0f);
    const int dst = ct * 1024 + ks * 512 + (qd * 16 + cl) * 8 + j;
    ((_Float16*)eh_t)[dst] = h;
    ((_Float16*)el_t)[dst] = l;
    float s = x * x;
#pragma unroll
    for (int off = 1; off <= 32; off <<= 1) s += __shfl_xor(s, off, 64);
    if (c == 0) {
        hnorms[k] = 0.5f * s;
        counts[k] = 0;
        if (k == 0) { *loss_acc = 0.f; *done_ctr = 0; }
    }
}

// 256 blocks x 1024 threads, 1 block/CU, 16 waves. waves_per_eu(4,4) pins the
// allocator's occupancy target at 4 waves/EU -> full 128-reg budget (LDS
// already caps occupancy, so these registers are free).
__global__ __attribute__((amdgpu_flat_work_group_size(1024, 1024)))
           __attribute__((amdgpu_waves_per_eu(4, 4)))
void vq_main(
    const float* __restrict__ in, const float* __restrict__ emb,
    const unsigned short* __restrict__ eh_t, const unsigned short* __restrict__ el_t,
    const float* __restrict__ hnorms, int* __restrict__ counts,
    float* __restrict__ loss_acc, int* __restrict__ done_ctr,
    float* __restrict__ dout)
{
    __shared__ __align__(16) _Float16 eh_l[KEMB * DDIM];   // 64 KB
    __shared__ __align__(16) _Float16 el_l[KEMB * DDIM];   // 64 KB
    __shared__ __align__(16) float hn_lds[KEMB];           // 2 KB
    __shared__ int hist[KEMB];                             // 2 KB
    __shared__ float part[8];
    __shared__ int lastflag;

    const int t    = threadIdx.x;         // 0..1023
    const int lane = t & 63;
    const int wv   = t >> 6;              // wave id 0..15
    const int quad = lane >> 4;
    const int col  = lane & 15;
    const int b    = blockIdx.x >> 3;                        // 8 blocks per image
    const int p0   = ((blockIdx.x & 7) << 9) | (wv << 5);    // first of this wave's 32 px
    const float* xb = in + b * BSTRIDE;

    if (t < KEMB) hist[t] = 0;
    if (t < 128) ((float4*)hn_lds)[t] = ((const float4*)hnorms)[t];

    // ---- Stage both tables into LDS: linear 16B/lane copies (proven).
#pragma unroll
    for (int i = 0; i < 4; ++i) {
        const int f = (t + i * 1024) * 8;
        *(f16x8*)&eh_l[f] = *(const f16x8*)((const _Float16*)eh_t + f);
        *(f16x8*)&el_l[f] = *(const f16x8*)((const _Float16*)el_t + f);
    }

    __syncthreads();   // tables + hn + hist ready

    // ---- Build x B-fragments AFTER the barrier (R9-proven): registers only.
    f16x8 xh[2][2], xl[2][2];
#pragma unroll
    for (int tt = 0; tt < 2; ++tt) {
#pragma unroll
        for (int s = 0; s < 2; ++s) {
            const int ppb = p0 + tt * 16 + col;
            const int c0  = s * 32 + quad * 8;
            f16x8 vh, vl;
#pragma unroll
            for (int j = 0; j < 8; ++j) {
                float x = xb[(c0 + j) * HW + ppb];
                _Float16 h = (_Float16)x;
                float r1 = x - (float)h;
                vh[j] = h;
                vl[j] = (_Float16)(r1 * 2048.0f);
            }
            xh[tt][s] = vh; xl[tt][s] = vl;
        }
    }

    // ---- K-loop over 32 code tiles — R9 VERBATIM (pure LDS + 12 MFMA/tile,
    // 1-tile prefetch pipeline, med3/min top-2).
    float v1[2], v2[2]; int k1[2], k2[2];
#pragma unroll
    for (int tt = 0; tt < 2; ++tt) {
        v1[tt] = 3.402823466e38f; v2[tt] = 3.402823466e38f; k1[tt] = 0; k2[tt] = 0;
    }

    f16x8 Ah0 = *(const f16x8*)&eh_l[lane * 8];
    f16x8 Ah1 = *(const f16x8*)&eh_l[lane * 8 + 512];
    f16x8 Al0 = *(const f16x8*)&el_l[lane * 8];
    f16x8 Al1 = *(const f16x8*)&el_l[lane * 8 + 512];

    for (int ct = 0; ct < 32; ++ct) {
        f32x4 a0h = (f32x4){0.f, 0.f, 0.f, 0.f};
        f32x4 a0l = (f32x4){0.f, 0.f, 0.f, 0.f};
        f32x4 a1h = (f32x4){0.f, 0.f, 0.f, 0.f};
        f32x4 a1l = (f32x4){0.f, 0.f, 0.f, 0.f};
        a0h = __builtin_amdgcn_mfma_f32_16x16x32_f16(Ah0, xh[0][0], a0h, 0, 0, 0);
        a0l = __builtin_amdgcn_mfma_f32_16x16x32_f16(Ah0, xl[0][0], a0l, 0, 0, 0);
        a0l = __builtin_amdgcn_mfma_f32_16x16x32_f16(Al0, xh[0][0], a0l, 0, 0, 0);
        a1h = __builtin_amdgcn_mfma_f32_16x16x32_f16(Ah0, xh[1][0], a1h, 0, 0, 0);
        a1l = __builtin_amdgcn_mfma_f32_16x16x32_f16(Ah0, xl[1][0], a1l, 0, 0, 0);
        a1l = __builtin_amdgcn_mfma_f32_16x16x32_f16(Al0, xh[1][0], a1l, 0, 0, 0);
        a0h = __builtin_amdgcn_mfma_f32_16x16x32_f16(Ah1, xh[0][1], a0h, 0, 0, 0);
        a0l = __builtin_amdgcn_mfma_f32_16x16x32_f16(Ah1, xl[0][1], a0l, 0, 0, 0);
        a0l = __builtin_amdgcn_mfma_f32_16x16x32_f16(Al1, xh[0][1], a0l, 0, 0, 0);
        a1h = __builtin_amdgcn_mfma_f32_16x16x32_f16(Ah1, xh[1][1], a1h, 0, 0, 0);
        a1l = __builtin_amdgcn_mfma_f32_16x16x32_f16(Ah1, xl[1][1], a1l, 0, 0, 0);
        a1l = __builtin_amdgcn_mfma_f32_16x16x32_f16(Al1, xh[1][1], a1l, 0, 0, 0);

        const int nbase = (((ct + 1) & 31) * 1024) + lane * 8;
        const f16x8 nAh0 = *(const f16x8*)&eh_l[nbase];
        const f16x8 nAh1 = *(const f16x8*)&eh_l[nbase + 512];
        const f16x8 nAl0 = *(const f16x8*)&el_l[nbase];
        const f16x8 nAl1 = *(const f16x8*)&el_l[nbase + 512];

        const f32x4 hn = *(const f32x4*)&hn_lds[ct * 16 + quad * 4];
#pragma unroll
        for (int r = 0; r < 4; ++r) {
            const int kk = ct * 16 + quad * 4 + r;
            {
                const float sc = hn[r] - (a0h[r] + a0l[r] * 4.8828125e-4f);
                const bool c1 = sc < v1[0];
                const bool c2 = sc < v2[0];
                const int nk2 = c1 ? k1[0] : (c2 ? kk : k2[0]);
                const int nk1 = c1 ? kk : k1[0];
                v2[0] = __builtin_amdgcn_fmed3f(v1[0], v2[0], sc);
                v1[0] = fminf(v1[0], sc);
                k1[0] = nk1; k2[0] = nk2;
            }
            {
                const float sc = hn[r] - (a1h[r] + a1l[r] * 4.8828125e-4f);
                const bool c1 = sc < v1[1];
                const bool c2 = sc < v2[1];
                const int nk2 = c1 ? k1[1] : (c2 ? kk : k2[1]);
                const int nk1 = c1 ? kk : k1[1];
                v2[1] = __builtin_amdgcn_fmed3f(v1[1], v2[1], sc);
                v1[1] = fminf(v1[1], sc);
                k1[1] = nk1; k2[1] = nk2;
            }
        }

        Ah0 = nAh0; Ah1 = nAh1; Al0 = nAl0; Al1 = nAl1;
    }

    // Cross-quad top-2 merge (lanes l, l^16, l^32 share pixel-col) — R0 verbatim
#pragma unroll
    for (int tt = 0; tt < 2; ++tt) {
#pragma unroll
        for (int off = 16; off <= 32; off <<= 1) {
            float w1 = __shfl_xor(v1[tt], off, 64); int j1 = __shfl_xor(k1[tt], off, 64);
            float w2 = __shfl_xor(v2[tt], off, 64); int j2 = __shfl_xor(k2[tt], off, 64);
            bool aF = (v1[tt] < w1) || (v1[tt] == w1 && k1[tt] < j1);
            float t1 = aF ? v1[tt] : w1;  int u1 = aF ? k1[tt] : j1;
            float tl = aF ? w1 : v1[tt];  int ul = aF ? j1 : k1[tt];      // loser of firsts
            bool bS = (v2[tt] < w2) || (v2[tt] == w2 && k2[tt] < j2);
            float tc = bS ? v2[tt] : w2;  int uc = bS ? k2[tt] : j2;      // better of seconds
            bool lS = (tl < tc) || (tl == tc && ul < uc);
            v1[tt] = t1; k1[tt] = u1;
            v2[tt] = lS ? tl : tc; k2[tt] = lS ? ul : uc;
        }
    }

    // Pixel q = lane&31; lanes l and l+32 handle the same pixel (tt = (l>>4)&1).
    const int q    = lane & 31;
    const int pp   = p0 + q;
    const int tsel = (lane >> 4) & 1;
    const int kA = tsel ? k1[1] : k1[0];
    const int kB = tsel ? k2[1] : k2[0];

    // Exact fp32 rescore, split: lanes<32 score kA, lanes>=32 score kB.
    // Op chain bitwise == R9. Each lane caches its half's x values (static
    // indices after unroll) for the full-wave output below.
    const bool hiHalf = (lane >= 32);
    const int kMine = hiHalf ? kB : kA;
    const float4* eM = (const float4*)(emb + kMine * DDIM);
    float xc[32];
    float a0 = hn_lds[kMine], a1 = 0.f, a2 = 0.f, a3 = 0.f;
#pragma unroll
    for (int i = 0; i < 16; ++i) {
        float4 ea = eM[i];
        const int c = i * 4;
        float x0 = xb[(c + 0) * HW + pp];
        float x1 = xb[(c + 1) * HW + pp];
        float x2 = xb[(c + 2) * HW + pp];
        float x3 = xb[(c + 3) * HW + pp];
        if (i < 8) {
            if (!hiHalf) { xc[i*4+0] = x0; xc[i*4+1] = x1; xc[i*4+2] = x2; xc[i*4+3] = x3; }
        } else {
            if (hiHalf)  { xc[(i-8)*4+0] = x0; xc[(i-8)*4+1] = x1; xc[(i-8)*4+2] = x2; xc[(i-8)*4+3] = x3; }
        }
        a0 = fmaf(-x0, ea.x, a0);
        a1 = fmaf(-x1, ea.y, a1);
        a2 = fmaf(-x2, ea.z, a2);
        a3 = fmaf(-x3, ea.w, a3);
    }
    const float dMine = (a0 + a1) + (a2 + a3);
    const float dOth  = __shfl_xor(dMine, 32, 64);
    const float dA = hiHalf ? dOth  : dMine;
    const float dB = hiHalf ? dMine : dOth;
    const int myk = (dB < dA || (dB == dA && kB < kA)) ? kB : kA;

    // Index + histogram once per pixel.
    if (!hiHalf) {
        dout[IDX_OFF + b * HW + pp] = (float)myk;
        atomicAdd(&hist[myk], 1);
    }

    // FULL-WAVE output: lane handles its half's 32 channels from cached x.
    // Out values bitwise == R9 (same qv - x / x + d ops on same inputs).
    float lsum = 0.f;
    {
        const float4* qrow = (const float4*)(emb + myk * DDIM);
        float* ob = dout + OUT_OFF + b * BSTRIDE;
        const int ci = hiHalf ? 8 : 0;   // float4 index base into qrow
#pragma unroll
        for (int i = 0; i < 8; ++i) {
            float4 qv = qrow[ci + i];
            const int c = (ci + i) * 4;
            float x0 = xc[i*4+0];
            float x1 = xc[i*4+1];
            float x2 = xc[i*4+2];
            float x3 = xc[i*4+3];
            float d0 = qv.x - x0;
            float d1 = qv.y - x1;
            float d2 = qv.z - x2;
            float d3 = qv.w - x3;
            lsum += d0 * d0 + d1 * d1 + d2 * d2 + d3 * d3;
            ob[(c + 0) * HW + pp] = x0 + d0;    // reference rounding: x + (q - x)
            ob[(c + 1) * HW + pp] = x1 + d1;
            ob[(c + 2) * HW + pp] = x2 + d2;
            ob[(c + 3) * HW + pp] = x3 + d3;
        }
    }
    for (int off = 32; off > 0; off >>= 1) lsum += __shfl_down(lsum, off, 64);
    if (lane == 0) atomicAdd(loss_acc, lsum);

    __syncthreads();
    if (t < KEMB) {
        int v = hist[t];
        if (v) atomicAdd(&counts[t], v);
    }

    // ---- Fused finalize, fence-LESS (R6/R8/R9-proven).
    __syncthreads();
    if (t == 0) lastflag = (atomicAdd(done_ctr, 1) == 255) ? 1 : 0;
    __syncthreads();
    if (lastflag) {
        if (t < KEMB) {
            int cnt = atomicAdd(&counts[t], 0);   // device-coherent read
            float pa = (float)cnt / (float)NPIX;
            float v = pa * logf(pa + 1e-10f);
#pragma unroll
            for (int off = 1; off <= 32; off <<= 1) v += __shfl_xor(v, off, 64);
            if ((t & 63) == 0) part[t >> 6] = v;
        }
        __syncthreads();
        if (t == 0) {
            float s = 0.f;
#pragma unroll
            for (int i = 0; i < 8; ++i) s += part[i];
            dout[PERP_OFF] = expf(-s);
            dout[0] = 0.25f * atomicAdd(loss_acc, 0.0f) / 8388608.0f;
        }
    }
}

extern "C" void kernel_launch(void* const* d_in, const int* in_sizes, int n_in,
                              void* d_out, int out_size, void* d_ws, size_t ws_size,
                              hipStream_t stream) {
    const float* in  = (const float*)d_in[0];   // 8388608 elems
    const float* emb = (const float*)d_in[1];   // 32768 elems
    float* dout = (float*)d_out;
    int*   counts   = (int*)d_ws;
    float* hnorms   = (float*)((char*)d_ws + 2048);
    float* loss_acc = (float*)((char*)d_ws + 4096);
    int*   done_ctr = (int*)((char*)d_ws + 4160);
    unsigned short* eh_t = (unsigned short*)((char*)d_ws + 8192);
    unsigned short* el_t = eh_t + KEMB * DDIM;   // 64 KB scaled-l table

    vq_init<<<512, 64, 0, stream>>>(emb, counts, hnorms, loss_acc, done_ctr, eh_t, el_t);
    vq_main<<<256, 1024, 0, stream>>>(in, emb, eh_t, el_t, hnorms, counts, loss_acc, done_ctr, dout);
}

// Round 15
// 154.464 us; speedup vs baseline: 1.1040x; 1.1040x over previous
//
#include <hip/hip_runtime.h>
#include <hip/hip_fp16.h>
#include <math.h>

// Problem constants
#define NPIX   131072      // B*H*W = 32*64*64
#define KEMB   512
#define DDIM   64
#define HW     4096        // H*W
#define BSTRIDE 262144     // C*H*W

// d_out flat layout (float32): [loss(1) | out(8388608) | perplexity(1) | indices(131072)]
#define OUT_OFF  1
#define PERP_OFF 8388609
#define IDX_OFF  8388610

typedef __attribute__((ext_vector_type(8))) _Float16 f16x8;    // MFMA A/B frag (4 VGPRs)
typedef __attribute__((ext_vector_type(4))) float f32x4;       // MFMA C/D frag

// SESSION LEDGER (proven on this problem):
//  - R9 = 82us vq_main (total 153.5, best): f16 2-split K-loop, both tables
//    LDS (132KB), 1-tile LDS prefetch pipeline, med3/min top-2, build-after-
//    barrier, 256x1024 @(1024,4), 16 waves/CU, fence-LESS ticket finalize.
//  - R13+R14: allocator pins 64 VGPRs on 1024-thr blocks and spills any
//    long-lived array past it; launch_bounds AND waves_per_eu both failed to
//    unlock 128. Register-cached epilogue is UNIMPLEMENTABLE here.
//  - R12: K-loop unroll x2 = +22us (scheduler collapse at the 64-reg pin).
//    K-loop source scheduling is DONE.
//  - R11: <=64-reg configs truly spill. Occupancy door CLOSED (16 waves/CU).
//  - R10 bundle (+gll, +early-loads, +setprio) = +4us; m190 says setprio is
//    negative in near-lockstep loops and R10's MfmaUtil DROPPED. R15 (this)
//    = the de-confound: R9 + gll staging + early build loads, NO setprio.
//    Both pieces proven reg-safe in R10 (no spill at VGPR=64).
//  - __threadfence() = ~2x curse (L2 WB/INV storm). NEVER.
//
// 2-split f16 scheme (absmax 0 in R2..R14): x = h + l/2048 + r, |r|<=2^-21|x|.
// l pre-scaled by 2^11 (exact pow2) stays in f16 normal range. Products kept:
// hh + (h*l'+l'*h)/2048; dropped terms ~1e-4 absolute, and the exact fp32
// top-2 rescore decides the final index.

// ws layout: [0,2048) int counts | [2048,4096) float hnorms | [4096] loss |
//            [4160] done_ctr | [8192,73728) eh_t (f16 high, frag-linear, 64KB) |
//            [73728,139264) el_t (f16 low pre-scaled by 2^11, frag-linear, 64KB)
// frag-linear: idx = ct*1024 + ks*512 + (quad*16+col)*8 + j  (R5-proven).
__global__ void vq_init(const float* __restrict__ emb, int* __restrict__ counts,
                        float* __restrict__ hnorms, float* __restrict__ loss_acc,
                        int* __restrict__ done_ctr,
                        unsigned short* __restrict__ eh_t,
                        unsigned short* __restrict__ el_t) {
    const int k = blockIdx.x;             // code
    const int c = threadIdx.x;            // channel
    const int ct = k >> 4, cl = k & 15;
    const int ks = c >> 5, qd = (c >> 3) & 3, j = c & 7;
    float x = emb[k * DDIM + c];
    _Float16 h = (_Float16)x;             // v_cvt_f16_f32, RTNE
    float r1 = x - (float)h;              // exact (Sterbenz)
    _Float16 l = (_Float16)(r1 * 2048.0f);
    const int dst = ct * 1024 + ks * 512 + (qd * 16 + cl) * 8 + j;
    ((_Float16*)eh_t)[dst] = h;
    ((_Float16*)el_t)[dst] = l;
    float s = x * x;
#pragma unroll
    for (int off = 1; off <= 32; off <<= 1) s += __shfl_xor(s, off, 64);
    if (c == 0) {
        hnorms[k] = 0.5f * s;
        counts[k] = 0;
        if (k == 0) { *loss_acc = 0.f; *done_ctr = 0; }
    }
}

// 256 blocks x 1024 threads, 1 block/CU, 16 waves (proven shape). LDS 132KB:
// both f16 tables resident -> K-loop pure LDS + 12 MFMA/tile, barrier-free,
// software-pipelined (R9 verbatim). Staging via global_load_lds DMA; build
// x loads issued before the DMA so they drain underneath it. NO setprio.
__global__ __launch_bounds__(1024, 4) void vq_main(
    const float* __restrict__ in, const float* __restrict__ emb,
    const unsigned short* __restrict__ eh_t, const unsigned short* __restrict__ el_t,
    const float* __restrict__ hnorms, int* __restrict__ counts,
    float* __restrict__ loss_acc, int* __restrict__ done_ctr,
    float* __restrict__ dout)
{
    __shared__ __align__(16) _Float16 eh_l[KEMB * DDIM];   // 64 KB
    __shared__ __align__(16) _Float16 el_l[KEMB * DDIM];   // 64 KB
    __shared__ __align__(16) float hn_lds[KEMB];           // 2 KB
    __shared__ int hist[KEMB];                             // 2 KB
    __shared__ float part[8];
    __shared__ int lastflag;

    const int t    = threadIdx.x;         // 0..1023
    const int lane = t & 63;
    const int wv   = t >> 6;              // wave id 0..15
    const int quad = lane >> 4;
    const int col  = lane & 15;
    const int b    = blockIdx.x >> 3;                        // 8 blocks per image
    const int p0   = ((blockIdx.x & 7) << 9) | (wv << 5);    // first of this wave's 32 px
    const float* xb = in + b * BSTRIDE;

    if (t < KEMB) hist[t] = 0;
    if (t < 128) ((float4*)hn_lds)[t] = ((const float4*)hnorms)[t];

    // ---- Issue the x build loads FIRST (32 regs, short-lived — R10-proven
    // reg-safe): they drain from L3/HBM while the staging DMA below runs.
    float xv[2][2][8];
#pragma unroll
    for (int tt = 0; tt < 2; ++tt)
#pragma unroll
        for (int s = 0; s < 2; ++s) {
            const int ppb = p0 + tt * 16 + col;
            const int c0  = s * 32 + quad * 8;
#pragma unroll
            for (int j = 0; j < 8; ++j)
                xv[tt][s][j] = xb[(c0 + j) * HW + ppb];
        }

    // ---- Stage both tables into LDS via direct L2->LDS DMA (16B/lane, the
    // wave-uniform-base + lane*16 linear pattern global_load_lds requires).
    // No VGPR round-trip, no ds_write. __syncthreads drains vmcnt for the DMA.
    // (R10-proven correct: absmax 0.)
#pragma unroll
    for (int i = 0; i < 4; ++i) {
        const int f = (t + i * 1024) * 8;   // halfword index, byte = 16*(t+i*1024)
        __builtin_amdgcn_global_load_lds((const __attribute__((address_space(1))) void*)((const _Float16*)eh_t + f),
                                         (__attribute__((address_space(3))) void*)&eh_l[f], 16, 0, 0);
        __builtin_amdgcn_global_load_lds((const __attribute__((address_space(1))) void*)((const _Float16*)el_t + f),
                                         (__attribute__((address_space(3))) void*)&el_l[f], 16, 0, 0);
    }

    // ---- Convert x to B-fragments (registers only) while the DMA completes.
    f16x8 xh[2][2], xl[2][2];
#pragma unroll
    for (int tt = 0; tt < 2; ++tt) {
#pragma unroll
        for (int s = 0; s < 2; ++s) {
            f16x8 vh, vl;
#pragma unroll
            for (int j = 0; j < 8; ++j) {
                float x = xv[tt][s][j];
                _Float16 h = (_Float16)x;
                float r1 = x - (float)h;
                vh[j] = h;
                vl[j] = (_Float16)(r1 * 2048.0f);
            }
            xh[tt][s] = vh; xl[tt][s] = vl;
        }
    }

    __syncthreads();   // tables + hn + hist ready; K-loop below is barrier-free

    // ---- K-loop over 32 code tiles — R9 VERBATIM (pure LDS + 12 MFMA/tile,
    // 1-tile prefetch pipeline, med3/min top-2). NO setprio.
    float v1[2], v2[2]; int k1[2], k2[2];
#pragma unroll
    for (int tt = 0; tt < 2; ++tt) {
        v1[tt] = 3.402823466e38f; v2[tt] = 3.402823466e38f; k1[tt] = 0; k2[tt] = 0;
    }

    f16x8 Ah0 = *(const f16x8*)&eh_l[lane * 8];
    f16x8 Ah1 = *(const f16x8*)&eh_l[lane * 8 + 512];
    f16x8 Al0 = *(const f16x8*)&el_l[lane * 8];
    f16x8 Al1 = *(const f16x8*)&el_l[lane * 8 + 512];

    for (int ct = 0; ct < 32; ++ct) {
        f32x4 a0h = (f32x4){0.f, 0.f, 0.f, 0.f};
        f32x4 a0l = (f32x4){0.f, 0.f, 0.f, 0.f};
        f32x4 a1h = (f32x4){0.f, 0.f, 0.f, 0.f};
        f32x4 a1l = (f32x4){0.f, 0.f, 0.f, 0.f};
        a0h = __builtin_amdgcn_mfma_f32_16x16x32_f16(Ah0, xh[0][0], a0h, 0, 0, 0);
        a0l = __builtin_amdgcn_mfma_f32_16x16x32_f16(Ah0, xl[0][0], a0l, 0, 0, 0);
        a0l = __builtin_amdgcn_mfma_f32_16x16x32_f16(Al0, xh[0][0], a0l, 0, 0, 0);
        a1h = __builtin_amdgcn_mfma_f32_16x16x32_f16(Ah0, xh[1][0], a1h, 0, 0, 0);
        a1l = __builtin_amdgcn_mfma_f32_16x16x32_f16(Ah0, xl[1][0], a1l, 0, 0, 0);
        a1l = __builtin_amdgcn_mfma_f32_16x16x32_f16(Al0, xh[1][0], a1l, 0, 0, 0);
        a0h = __builtin_amdgcn_mfma_f32_16x16x32_f16(Ah1, xh[0][1], a0h, 0, 0, 0);
        a0l = __builtin_amdgcn_mfma_f32_16x16x32_f16(Ah1, xl[0][1], a0l, 0, 0, 0);
        a0l = __builtin_amdgcn_mfma_f32_16x16x32_f16(Al1, xh[0][1], a0l, 0, 0, 0);
        a1h = __builtin_amdgcn_mfma_f32_16x16x32_f16(Ah1, xh[1][1], a1h, 0, 0, 0);
        a1l = __builtin_amdgcn_mfma_f32_16x16x32_f16(Ah1, xl[1][1], a1l, 0, 0, 0);
        a1l = __builtin_amdgcn_mfma_f32_16x16x32_f16(Al1, xh[1][1], a1l, 0, 0, 0);

        const int nbase = (((ct + 1) & 31) * 1024) + lane * 8;
        const f16x8 nAh0 = *(const f16x8*)&eh_l[nbase];
        const f16x8 nAh1 = *(const f16x8*)&eh_l[nbase + 512];
        const f16x8 nAl0 = *(const f16x8*)&el_l[nbase];
        const f16x8 nAl1 = *(const f16x8*)&el_l[nbase + 512];

        const f32x4 hn = *(const f32x4*)&hn_lds[ct * 16 + quad * 4];
#pragma unroll
        for (int r = 0; r < 4; ++r) {
            const int kk = ct * 16 + quad * 4 + r;
            {
                const float sc = hn[r] - (a0h[r] + a0l[r] * 4.8828125e-4f);
                const bool c1 = sc < v1[0];
                const bool c2 = sc < v2[0];
                const int nk2 = c1 ? k1[0] : (c2 ? kk : k2[0]);
                const int nk1 = c1 ? kk : k1[0];
                v2[0] = __builtin_amdgcn_fmed3f(v1[0], v2[0], sc);
                v1[0] = fminf(v1[0], sc);
                k1[0] = nk1; k2[0] = nk2;
            }
            {
                const float sc = hn[r] - (a1h[r] + a1l[r] * 4.8828125e-4f);
                const bool c1 = sc < v1[1];
                const bool c2 = sc < v2[1];
                const int nk2 = c1 ? k1[1] : (c2 ? kk : k2[1]);
                const int nk1 = c1 ? kk : k1[1];
                v2[1] = __builtin_amdgcn_fmed3f(v1[1], v2[1], sc);
                v1[1] = fminf(v1[1], sc);
                k1[1] = nk1; k2[1] = nk2;
            }
        }

        Ah0 = nAh0; Ah1 = nAh1; Al0 = nAl0; Al1 = nAl1;
    }

    // Cross-quad top-2 merge (lanes l, l^16, l^32 share pixel-col) — R0 verbatim
#pragma unroll
    for (int tt = 0; tt < 2; ++tt) {
#pragma unroll
        for (int off = 16; off <= 32; off <<= 1) {
            float w1 = __shfl_xor(v1[tt], off, 64); int j1 = __shfl_xor(k1[tt], off, 64);
            float w2 = __shfl_xor(v2[tt], off, 64); int j2 = __shfl_xor(k2[tt], off, 64);
            bool aF = (v1[tt] < w1) || (v1[tt] == w1 && k1[tt] < j1);
            float t1 = aF ? v1[tt] : w1;  int u1 = aF ? k1[tt] : j1;
            float tl = aF ? w1 : v1[tt];  int ul = aF ? j1 : k1[tt];      // loser of firsts
            bool bS = (v2[tt] < w2) || (v2[tt] == w2 && k2[tt] < j2);
            float tc = bS ? v2[tt] : w2;  int uc = bS ? k2[tt] : j2;      // better of seconds
            bool lS = (tl < tc) || (tl == tc && ul < uc);
            v1[tt] = t1; k1[tt] = u1;
            v2[tt] = lS ? tl : tc; k2[tt] = lS ? ul : uc;
        }
    }

    // Pixel q = lane&31; lanes l and l+32 handle the same pixel (tt = (l>>4)&1).
    const int q    = lane & 31;
    const int pp   = p0 + q;
    const int tsel = (lane >> 4) & 1;
    const int kA = tsel ? k1[1] : k1[0];
    const int kB = tsel ? k2[1] : k2[0];

    // Exact fp32 rescore, split: lanes<32 score kA, lanes>=32 score kB.
    // Streaming x loads — ops and order bitwise == the passing kernels.
    const int kMine = (lane < 32) ? kA : kB;
    const float4* eM = (const float4*)(emb + kMine * DDIM);
    float a0 = hn_lds[kMine], a1 = 0.f, a2 = 0.f, a3 = 0.f;
#pragma unroll
    for (int i = 0; i < 16; ++i) {
        float4 ea = eM[i];
        const int c = i * 4;
        float x0 = xb[(c + 0) * HW + pp];
        float x1 = xb[(c + 1) * HW + pp];
        float x2 = xb[(c + 2) * HW + pp];
        float x3 = xb[(c + 3) * HW + pp];
        a0 = fmaf(-x0, ea.x, a0);
        a1 = fmaf(-x1, ea.y, a1);
        a2 = fmaf(-x2, ea.z, a2);
        a3 = fmaf(-x3, ea.w, a3);
    }
    const float dMine = (a0 + a1) + (a2 + a3);
    const float dOth  = __shfl_xor(dMine, 32, 64);
    const float dA = (lane < 32) ? dMine : dOth;
    const float dB = (lane < 32) ? dOth  : dMine;
    const int myk = (dB < dA || (dB == dA && kB < kA)) ? kB : kA;

    float lsum = 0.f;
    if (lane < 32) {
        dout[IDX_OFF + b * HW + pp] = (float)myk;
        atomicAdd(&hist[myk], 1);
        const float4* qrow = (const float4*)(emb + myk * DDIM);
        float* ob = dout + OUT_OFF + b * BSTRIDE;
#pragma unroll
        for (int i = 0; i < 16; ++i) {
            float4 qv = qrow[i];
            const int c = i * 4;
            float x0 = xb[(c + 0) * HW + pp];   // L1-warm reload (just read above)
            float x1 = xb[(c + 1) * HW + pp];
            float x2 = xb[(c + 2) * HW + pp];
            float x3 = xb[(c + 3) * HW + pp];
            float d0 = qv.x - x0;
            float d1 = qv.y - x1;
            float d2 = qv.z - x2;
            float d3 = qv.w - x3;
            lsum += d0 * d0 + d1 * d1 + d2 * d2 + d3 * d3;
            ob[(c + 0) * HW + pp] = x0 + d0;    // reference rounding: x + (q - x)
            ob[(c + 1) * HW + pp] = x1 + d1;
            ob[(c + 2) * HW + pp] = x2 + d2;
            ob[(c + 3) * HW + pp] = x3 + d3;
        }
    }
    for (int off = 32; off > 0; off >>= 1) lsum += __shfl_down(lsum, off, 64);
    if (lane == 0) atomicAdd(loss_acc, lsum);

    __syncthreads();
    if (t < KEMB) {
        int v = hist[t];
        if (v) atomicAdd(&counts[t], v);
    }

    // ---- Fused finalize, fence-LESS (R6/R8/R9-proven).
    __syncthreads();
    if (t == 0) lastflag = (atomicAdd(done_ctr, 1) == 255) ? 1 : 0;
    __syncthreads();
    if (lastflag) {
        if (t < KEMB) {
            int cnt = atomicAdd(&counts[t], 0);   // device-coherent read
            float pa = (float)cnt / (float)NPIX;
            float v = pa * logf(pa + 1e-10f);
#pragma unroll
            for (int off = 1; off <= 32; off <<= 1) v += __shfl_xor(v, off, 64);
            if ((t & 63) == 0) part[t >> 6] = v;
        }
        __syncthreads();
        if (t == 0) {
            float s = 0.f;
#pragma unroll
            for (int i = 0; i < 8; ++i) s += part[i];
            dout[PERP_OFF] = expf(-s);
            dout[0] = 0.25f * atomicAdd(loss_acc, 0.0f) / 8388608.0f;
        }
    }
}

extern "C" void kernel_launch(void* const* d_in, const int* in_sizes, int n_in,
                              void* d_out, int out_size, void* d_ws, size_t ws_size,
                              hipStream_t stream) {
    const float* in  = (const float*)d_in[0];   // 8388608 elems
    const float* emb = (const float*)d_in[1];   // 32768 elems
    float* dout = (float*)d_out;
    int*   counts   = (int*)d_ws;
    float* hnorms   = (float*)((char*)d_ws + 2048);
    float* loss_acc = (float*)((char*)d_ws + 4096);
    int*   done_ctr = (int*)((char*)d_ws + 4160);
    unsigned short* eh_t = (unsigned short*)((char*)d_ws + 8192);
    unsigned short* el_t = eh_t + KEMB * DDIM;   // 64 KB scaled-l table

    vq_init<<<512, 64, 0, stream>>>(emb, counts, hnorms, loss_acc, done_ctr, eh_t, el_t);
    vq_main<<<256, 1024, 0, stream>>>(in, emb, eh_t, el_t, hnorms, counts, loss_acc, done_ctr, dout);
}

// Round 16
// 154.299 us; speedup vs baseline: 1.1052x; 1.0011x over previous
//
#include <hip/hip_runtime.h>
#include <hip/hip_fp16.h>
#include <math.h>

// Problem constants
#define NPIX   131072      // B*H*W = 32*64*64
#define KEMB   512
#define DDIM   64
#define HW     4096        // H*W
#define BSTRIDE 262144     // C*H*W

// d_out flat layout (float32): [loss(1) | out(8388608) | perplexity(1) | indices(131072)]
#define OUT_OFF  1
#define PERP_OFF 8388609
#define IDX_OFF  8388610

typedef __attribute__((ext_vector_type(8))) _Float16 f16x8;    // MFMA A/B frag (4 VGPRs)
typedef __attribute__((ext_vector_type(4))) float f32x4;       // MFMA C/D frag

// SESSION LEDGER (proven on this problem):
//  - R9 = 82us vq_main (total 153.5, best): f16 2-split K-loop, both tables
//    LDS (132KB), 1-tile LDS prefetch pipeline, med3/min top-2, build-after-
//    barrier, 256x1024 @(1024,4), 16 waves/CU, fence-LESS ticket finalize,
//    plain reg-staged LDS copies (gll variant R15 was -2us: DMA serializes
//    behind the same vmcnt drain as the early x loads).
//  - R13+R14: allocator pins 64 VGPRs on 1024-thr blocks; any long-lived
//    array past it spills (launch_bounds AND waves_per_eu failed to unlock
//    128). NO register-cached epilogue.
//  - R12: K-loop unroll x2 = +22us. K-loop source scheduling is DONE.
//  - R11: <=64-reg configs truly spill. Occupancy door CLOSED (16 waves/CU).
//  - R10/R15 de-confound: setprio ~-2us, gll+early-loads ~-2us. Both dropped.
//  - __threadfence() = ~2x curse (L2 WB/INV storm). NEVER.
//  - R16 (this): ONLY change vs R9 = full-wave output split WITHOUT x-cache:
//    lane l writes channels 0-31, lane l+32 writes 32-63 of the shared pixel,
//    x reloaded from L1 (warm: every lane loaded all 64 channels in rescore).
//    16 serial output iters -> 8, idle half-wave activated, zero new live
//    state. Per-element out arithmetic bitwise == R9; lsum lane-partition
//    changes only the loss scalar's reduction order (R13-proven acceptable).
//
// 2-split f16 scheme (absmax 0 in R2..R15): x = h + l/2048 + r, |r|<=2^-21|x|.
// l pre-scaled by 2^11 (exact pow2) stays in f16 normal range. Products kept:
// hh + (h*l'+l'*h)/2048; dropped terms ~1e-4 absolute, and the exact fp32
// top-2 rescore decides the final index.

// ws layout: [0,2048) int counts | [2048,4096) float hnorms | [4096] loss |
//            [4160] done_ctr | [8192,73728) eh_t (f16 high, frag-linear, 64KB) |
//            [73728,139264) el_t (f16 low pre-scaled by 2^11, frag-linear, 64KB)
// frag-linear: idx = ct*1024 + ks*512 + (quad*16+col)*8 + j  (R5-proven).
__global__ void vq_init(const float* __restrict__ emb, int* __restrict__ counts,
                        float* __restrict__ hnorms, float* __restrict__ loss_acc,
                        int* __restrict__ done_ctr,
                        unsigned short* __restrict__ eh_t,
                        unsigned short* __restrict__ el_t) {
    const int k = blockIdx.x;             // code
    const int c = threadIdx.x;            // channel
    const int ct = k >> 4, cl = k & 15;
    const int ks = c >> 5, qd = (c >> 3) & 3, j = c & 7;
    float x = emb[k * DDIM + c];
    _Float16 h = (_Float16)x;             // v_cvt_f16_f32, RTNE
    float r1 = x - (float)h;              // exact (Sterbenz)
    _Float16 l = (_Float16)(r1 * 2048.0f);
    const int dst = ct * 1024 + ks * 512 + (qd * 16 + cl) * 8 + j;
    ((_Float16*)eh_t)[dst] = h;
    ((_Float16*)el_t)[dst] = l;
    float s = x * x;
#pragma unroll
    for (int off = 1; off <= 32; off <<= 1) s += __shfl_xor(s, off, 64);
    if (c == 0) {
        hnorms[k] = 0.5f * s;
        counts[k] = 0;
        if (k == 0) { *loss_acc = 0.f; *done_ctr = 0; }
    }
}

// 256 blocks x 1024 threads, 1 block/CU, 16 waves (proven shape). LDS 132KB:
// both f16 tables resident -> K-loop pure LDS + 12 MFMA/tile, barrier-free,
// software-pipelined (R9 verbatim). Epilogue: full-wave split output.
__global__ __launch_bounds__(1024, 4) void vq_main(
    const float* __restrict__ in, const float* __restrict__ emb,
    const unsigned short* __restrict__ eh_t, const unsigned short* __restrict__ el_t,
    const float* __restrict__ hnorms, int* __restrict__ counts,
    float* __restrict__ loss_acc, int* __restrict__ done_ctr,
    float* __restrict__ dout)
{
    __shared__ __align__(16) _Float16 eh_l[KEMB * DDIM];   // 64 KB
    __shared__ __align__(16) _Float16 el_l[KEMB * DDIM];   // 64 KB
    __shared__ __align__(16) float hn_lds[KEMB];           // 2 KB
    __shared__ int hist[KEMB];                             // 2 KB
    __shared__ float part[8];
    __shared__ int lastflag;

    const int t    = threadIdx.x;         // 0..1023
    const int lane = t & 63;
    const int wv   = t >> 6;              // wave id 0..15
    const int quad = lane >> 4;
    const int col  = lane & 15;
    const int b    = blockIdx.x >> 3;                        // 8 blocks per image
    const int p0   = ((blockIdx.x & 7) << 9) | (wv << 5);    // first of this wave's 32 px
    const float* xb = in + b * BSTRIDE;

    if (t < KEMB) hist[t] = 0;
    if (t < 128) ((float4*)hn_lds)[t] = ((const float4*)hnorms)[t];

    // ---- Stage both tables into LDS: linear 16B/lane copies (R9-proven).
#pragma unroll
    for (int i = 0; i < 4; ++i) {
        const int f = (t + i * 1024) * 8;
        *(f16x8*)&eh_l[f] = *(const f16x8*)((const _Float16*)eh_t + f);
        *(f16x8*)&el_l[f] = *(const f16x8*)((const _Float16*)el_t + f);
    }

    __syncthreads();   // tables + hn + hist ready

    // ---- Build x B-fragments AFTER the barrier (R9-proven): registers only.
    f16x8 xh[2][2], xl[2][2];
#pragma unroll
    for (int tt = 0; tt < 2; ++tt) {
#pragma unroll
        for (int s = 0; s < 2; ++s) {
            const int ppb = p0 + tt * 16 + col;
            const int c0  = s * 32 + quad * 8;
            f16x8 vh, vl;
#pragma unroll
            for (int j = 0; j < 8; ++j) {
                float x = xb[(c0 + j) * HW + ppb];
                _Float16 h = (_Float16)x;
                float r1 = x - (float)h;
                vh[j] = h;
                vl[j] = (_Float16)(r1 * 2048.0f);
            }
            xh[tt][s] = vh; xl[tt][s] = vl;
        }
    }

    // ---- K-loop over 32 code tiles — R9 VERBATIM (pure LDS + 12 MFMA/tile,
    // 1-tile prefetch pipeline, med3/min top-2).
    float v1[2], v2[2]; int k1[2], k2[2];
#pragma unroll
    for (int tt = 0; tt < 2; ++tt) {
        v1[tt] = 3.402823466e38f; v2[tt] = 3.402823466e38f; k1[tt] = 0; k2[tt] = 0;
    }

    f16x8 Ah0 = *(const f16x8*)&eh_l[lane * 8];
    f16x8 Ah1 = *(const f16x8*)&eh_l[lane * 8 + 512];
    f16x8 Al0 = *(const f16x8*)&el_l[lane * 8];
    f16x8 Al1 = *(const f16x8*)&el_l[lane * 8 + 512];

    for (int ct = 0; ct < 32; ++ct) {
        f32x4 a0h = (f32x4){0.f, 0.f, 0.f, 0.f};
        f32x4 a0l = (f32x4){0.f, 0.f, 0.f, 0.f};
        f32x4 a1h = (f32x4){0.f, 0.f, 0.f, 0.f};
        f32x4 a1l = (f32x4){0.f, 0.f, 0.f, 0.f};
        a0h = __builtin_amdgcn_mfma_f32_16x16x32_f16(Ah0, xh[0][0], a0h, 0, 0, 0);
        a0l = __builtin_amdgcn_mfma_f32_16x16x32_f16(Ah0, xl[0][0], a0l, 0, 0, 0);
        a0l = __builtin_amdgcn_mfma_f32_16x16x32_f16(Al0, xh[0][0], a0l, 0, 0, 0);
        a1h = __builtin_amdgcn_mfma_f32_16x16x32_f16(Ah0, xh[1][0], a1h, 0, 0, 0);
        a1l = __builtin_amdgcn_mfma_f32_16x16x32_f16(Ah0, xl[1][0], a1l, 0, 0, 0);
        a1l = __builtin_amdgcn_mfma_f32_16x16x32_f16(Al0, xh[1][0], a1l, 0, 0, 0);
        a0h = __builtin_amdgcn_mfma_f32_16x16x32_f16(Ah1, xh[0][1], a0h, 0, 0, 0);
        a0l = __builtin_amdgcn_mfma_f32_16x16x32_f16(Ah1, xl[0][1], a0l, 0, 0, 0);
        a0l = __builtin_amdgcn_mfma_f32_16x16x32_f16(Al1, xh[0][1], a0l, 0, 0, 0);
        a1h = __builtin_amdgcn_mfma_f32_16x16x32_f16(Ah1, xh[1][1], a1h, 0, 0, 0);
        a1l = __builtin_amdgcn_mfma_f32_16x16x32_f16(Ah1, xl[1][1], a1l, 0, 0, 0);
        a1l = __builtin_amdgcn_mfma_f32_16x16x32_f16(Al1, xh[1][1], a1l, 0, 0, 0);

        const int nbase = (((ct + 1) & 31) * 1024) + lane * 8;
        const f16x8 nAh0 = *(const f16x8*)&eh_l[nbase];
        const f16x8 nAh1 = *(const f16x8*)&eh_l[nbase + 512];
        const f16x8 nAl0 = *(const f16x8*)&el_l[nbase];
        const f16x8 nAl1 = *(const f16x8*)&el_l[nbase + 512];

        const f32x4 hn = *(const f32x4*)&hn_lds[ct * 16 + quad * 4];
#pragma unroll
        for (int r = 0; r < 4; ++r) {
            const int kk = ct * 16 + quad * 4 + r;
            {
                const float sc = hn[r] - (a0h[r] + a0l[r] * 4.8828125e-4f);
                const bool c1 = sc < v1[0];
                const bool c2 = sc < v2[0];
                const int nk2 = c1 ? k1[0] : (c2 ? kk : k2[0]);
                const int nk1 = c1 ? kk : k1[0];
                v2[0] = __builtin_amdgcn_fmed3f(v1[0], v2[0], sc);
                v1[0] = fminf(v1[0], sc);
                k1[0] = nk1; k2[0] = nk2;
            }
            {
                const float sc = hn[r] - (a1h[r] + a1l[r] * 4.8828125e-4f);
                const bool c1 = sc < v1[1];
                const bool c2 = sc < v2[1];
                const int nk2 = c1 ? k1[1] : (c2 ? kk : k2[1]);
                const int nk1 = c1 ? kk : k1[1];
                v2[1] = __builtin_amdgcn_fmed3f(v1[1], v2[1], sc);
                v1[1] = fminf(v1[1], sc);
                k1[1] = nk1; k2[1] = nk2;
            }
        }

        Ah0 = nAh0; Ah1 = nAh1; Al0 = nAl0; Al1 = nAl1;
    }

    // Cross-quad top-2 merge (lanes l, l^16, l^32 share pixel-col) — R0 verbatim
#pragma unroll
    for (int tt = 0; tt < 2; ++tt) {
#pragma unroll
        for (int off = 16; off <= 32; off <<= 1) {
            float w1 = __shfl_xor(v1[tt], off, 64); int j1 = __shfl_xor(k1[tt], off, 64);
            float w2 = __shfl_xor(v2[tt], off, 64); int j2 = __shfl_xor(k2[tt], off, 64);
            bool aF = (v1[tt] < w1) || (v1[tt] == w1 && k1[tt] < j1);
            float t1 = aF ? v1[tt] : w1;  int u1 = aF ? k1[tt] : j1;
            float tl = aF ? w1 : v1[tt];  int ul = aF ? j1 : k1[tt];      // loser of firsts
            bool bS = (v2[tt] < w2) || (v2[tt] == w2 && k2[tt] < j2);
            float tc = bS ? v2[tt] : w2;  int uc = bS ? k2[tt] : j2;      // better of seconds
            bool lS = (tl < tc) || (tl == tc && ul < uc);
            v1[tt] = t1; k1[tt] = u1;
            v2[tt] = lS ? tl : tc; k2[tt] = lS ? ul : uc;
        }
    }

    // Pixel q = lane&31; lanes l and l+32 handle the same pixel (tt = (l>>4)&1).
    const int q    = lane & 31;
    const int pp   = p0 + q;
    const int tsel = (lane >> 4) & 1;
    const int kA = tsel ? k1[1] : k1[0];
    const int kB = tsel ? k2[1] : k2[0];

    // Exact fp32 rescore, split: lanes<32 score kA, lanes>=32 score kB.
    // Streaming x loads — ops and order bitwise == R9 (all lanes read all 64
    // channels, leaving L1 warm for the split output below).
    const bool hiHalf = (lane >= 32);
    const int kMine = hiHalf ? kB : kA;
    const float4* eM = (const float4*)(emb + kMine * DDIM);
    float a0 = hn_lds[kMine], a1 = 0.f, a2 = 0.f, a3 = 0.f;
#pragma unroll
    for (int i = 0; i < 16; ++i) {
        float4 ea = eM[i];
        const int c = i * 4;
        float x0 = xb[(c + 0) * HW + pp];
        float x1 = xb[(c + 1) * HW + pp];
        float x2 = xb[(c + 2) * HW + pp];
        float x3 = xb[(c + 3) * HW + pp];
        a0 = fmaf(-x0, ea.x, a0);
        a1 = fmaf(-x1, ea.y, a1);
        a2 = fmaf(-x2, ea.z, a2);
        a3 = fmaf(-x3, ea.w, a3);
    }
    const float dMine = (a0 + a1) + (a2 + a3);
    const float dOth  = __shfl_xor(dMine, 32, 64);
    const float dA = hiHalf ? dOth  : dMine;
    const float dB = hiHalf ? dMine : dOth;
    const int myk = (dB < dA || (dB == dA && kB < kA)) ? kB : kA;

    // Index + histogram once per pixel.
    if (!hiHalf) {
        dout[IDX_OFF + b * HW + pp] = (float)myk;
        atomicAdd(&hist[myk], 1);
    }

    // FULL-WAVE split output: lane handles its half's 32 channels, reloading
    // x from warm L1 (no register cache — R13/R14 proved arrays spill).
    // Out values bitwise == R9 (same qv - x / x + d ops on same inputs).
    float lsum = 0.f;
    {
        const float4* qrow = (const float4*)(emb + myk * DDIM);
        float* ob = dout + OUT_OFF + b * BSTRIDE;
        const int ci = hiHalf ? 8 : 0;   // float4 index base into qrow
#pragma unroll
        for (int i = 0; i < 8; ++i) {
            float4 qv = qrow[ci + i];
            const int c = (ci + i) * 4;
            float x0 = xb[(c + 0) * HW + pp];   // L1-warm reload (rescore just read it)
            float x1 = xb[(c + 1) * HW + pp];
            float x2 = xb[(c + 2) * HW + pp];
            float x3 = xb[(c + 3) * HW + pp];
            float d0 = qv.x - x0;
            float d1 = qv.y - x1;
            float d2 = qv.z - x2;
            float d3 = qv.w - x3;
            lsum += d0 * d0 + d1 * d1 + d2 * d2 + d3 * d3;
            ob[(c + 0) * HW + pp] = x0 + d0;    // reference rounding: x + (q - x)
            ob[(c + 1) * HW + pp] = x1 + d1;
            ob[(c + 2) * HW + pp] = x2 + d2;
            ob[(c + 3) * HW + pp] = x3 + d3;
        }
    }
    for (int off = 32; off > 0; off >>= 1) lsum += __shfl_down(lsum, off, 64);
    if (lane == 0) atomicAdd(loss_acc, lsum);

    __syncthreads();
    if (t < KEMB) {
        int v = hist[t];
        if (v) atomicAdd(&counts[t], v);
    }

    // ---- Fused finalize, fence-LESS (R6/R8/R9-proven).
    __syncthreads();
    if (t == 0) lastflag = (atomicAdd(done_ctr, 1) == 255) ? 1 : 0;
    __syncthreads();
    if (lastflag) {
        if (t < KEMB) {
            int cnt = atomicAdd(&counts[t], 0);   // device-coherent read
            float pa = (float)cnt / (float)NPIX;
            float v = pa * logf(pa + 1e-10f);
#pragma unroll
            for (int off = 1; off <= 32; off <<= 1) v += __shfl_xor(v, off, 64);
            if ((t & 63) == 0) part[t >> 6] = v;
        }
        __syncthreads();
        if (t == 0) {
            float s = 0.f;
#pragma unroll
            for (int i = 0; i < 8; ++i) s += part[i];
            dout[PERP_OFF] = expf(-s);
            dout[0] = 0.25f * atomicAdd(loss_acc, 0.0f) / 8388608.0f;
        }
    }
}

extern "C" void kernel_launch(void* const* d_in, const int* in_sizes, int n_in,
                              void* d_out, int out_size, void* d_ws, size_t ws_size,
                              hipStream_t stream) {
    const float* in  = (const float*)d_in[0];   // 8388608 elems
    const float* emb = (const float*)d_in[1];   // 32768 elems
    float* dout = (float*)d_out;
    int*   counts   = (int*)d_ws;
    float* hnorms   = (float*)((char*)d_ws + 2048);
    float* loss_acc = (float*)((char*)d_ws + 4096);
    int*   done_ctr = (int*)((char*)d_ws + 4160);
    unsigned short* eh_t = (unsigned short*)((char*)d_ws + 8192);
    unsigned short* el_t = eh_t + KEMB * DDIM;   // 64 KB scaled-l table

    vq_init<<<512, 64, 0, stream>>>(emb, counts, hnorms, loss_acc, done_ctr, eh_t, el_t);
    vq_main<<<256, 1024, 0, stream>>>(in, emb, eh_t, el_t, hnorms, counts, loss_acc, done_ctr, dout);
}